// Round 1
// baseline (103.180 us; speedup 1.0000x reference)
//
#include <hip/hip_runtime.h>
#include <math.h>

// Problem constants (match reference)
constexpr int   B_    = 2048;
constexpr int   L_    = 8192;
constexpr int   G_    = 256;
constexpr float BETA_ = 0.01f;
constexpr float BIG_  = 1024.0f;   // y-flag encoding (validated absmax 0.0 in prior rounds)

// log(sigmoid(-x)) = -softplus(x) = -(max(x,0) + log(1 + exp(-|x|)))
__device__ __forceinline__ float log_sigmoid_neg(float x) {
    return -(fmaxf(x, 0.0f) + __logf(1.0f + __expf(-fabsf(x))));
}

// ---------------------------------------------------------------------------
// Prep: pack group_ids (int32, values 0..255) into u8 — 8 KB, L2-hot for all
// 2048 main blocks. Replaces the counting-sort/rank machinery entirely.
// ---------------------------------------------------------------------------
extern "C" __global__ __launch_bounds__(1024)
void pack_gid_kernel(const int* __restrict__ group_ids,
                     unsigned int* __restrict__ gid8)
{
    const int j = blockIdx.x * 1024 + threadIdx.x;        // 0..2047
    const int4 g = ((const int4*)group_ids)[j];
    gid8[j] = (unsigned)(g.x & 255) | ((unsigned)(g.y & 255) << 8) |
              ((unsigned)(g.z & 255) << 16) | ((unsigned)(g.w & 255) << 24);
}

// ---------------------------------------------------------------------------
// Main: one 256-thread block (4 waves) per row.
//  - Per-WAVE private accumulator s_acc[wave][256]: ds_add_f32 scatter, no
//    inter-wave same-address contention; 64 lanes over 256 slots ~ 2-way bank
//    aliasing (free per m136).
//  - LDS 4.2 KB, VGPR-capped for 8 waves/SIMD -> 8 blocks/CU -> the entire
//    grid (2048 blocks x 4 waves = 8192 waves) is resident at once.
//  - Finalize: thread t owns group t (all 256 threads active), BIG-decode,
//    clamp, block-reduce, one global atomic per block.
// ---------------------------------------------------------------------------
extern "C" __global__ __launch_bounds__(256, 8)
void meta_loss_kernel(const float* __restrict__ logits,
                      const int*   __restrict__ true_y,
                      const unsigned int* __restrict__ gid8,
                      float*       __restrict__ out)
{
    __shared__ float s_acc[4][G_];    // 4 KB: per-wave group accumulators
    __shared__ float s_part[4];

    const int t  = threadIdx.x;       // 0..255
    const int b  = blockIdx.x;
    const int wv = t >> 6;

    // preload group bytes (L2-hot) while zero-init + barrier happen
    unsigned gbuf[8];
    #pragma unroll
    for (int i = 0; i < 8; ++i) gbuf[i] = gid8[i * 256 + t];

    // zero accumulators: 1024 floats / 256 threads = 1 float4 each
    ((float4*)s_acc)[t] = make_float4(0.f, 0.f, 0.f, 0.f);
    __syncthreads();

    const float4* lg  = (const float4*)(logits + (size_t)b * L_);
    const int4*   ty  = (const int4*)(true_y + (size_t)b * L_);
    float*        acc = s_acc[wv];

    #pragma unroll
    for (int i = 0; i < 8; ++i) {
        const int idx = i * 256 + t;
        const float4   x  = lg[idx];
        const int4     y  = ty[idx];
        const unsigned g4 = gbuf[i];
        atomicAdd(&acc[ g4        & 255u], log_sigmoid_neg(x.x) + (y.x ? BIG_ : 0.0f));
        atomicAdd(&acc[(g4 >>  8) & 255u], log_sigmoid_neg(x.y) + (y.y ? BIG_ : 0.0f));
        atomicAdd(&acc[(g4 >> 16) & 255u], log_sigmoid_neg(x.z) + (y.z ? BIG_ : 0.0f));
        atomicAdd(&acc[ g4 >> 24        ], log_sigmoid_neg(x.w) + (y.w ? BIG_ : 0.0f));
    }
    __syncthreads();

    // ---- finalize: group t ----
    const float enc = (s_acc[0][t] + s_acc[1][t]) + (s_acc[2][t] + s_acc[3][t]);
    const int   k   = __float2int_rn(enc * (1.0f / BIG_));   // # true labels
    const float gl  = enc - BIG_ * (float)k;                 // sum log(1-sig)

    float term;
    if (k != 0) {
        term = fmaxf(gl, -100.0f);                    // meta_y = 1: log(p)
    } else {
        // empty group: gl==0 -> log1p(-1) = -inf -> clamped to -100 (matches ref)
        term = fmaxf(log1pf(-__expf(gl)), -100.0f);   // meta_y = 0
    }

    // block reduction (4 waves)
    #pragma unroll
    for (int off = 32; off > 0; off >>= 1)
        term += __shfl_down(term, off, 64);
    if ((t & 63) == 0) s_part[wv] = term;
    __syncthreads();

    if (t == 0) {
        const float s = (s_part[0] + s_part[1]) + (s_part[2] + s_part[3]);
        atomicAdd(out, s * (-BETA_ / ((float)B_ * (float)G_)));
    }
}

extern "C" void kernel_launch(void* const* d_in, const int* in_sizes, int n_in,
                              void* d_out, int out_size, void* d_ws, size_t ws_size,
                              hipStream_t stream) {
    const float* logits    = (const float*)d_in[0];
    const int*   true_y    = (const int*)d_in[1];
    const int*   group_ids = (const int*)d_in[2];
    float*       out       = (float*)d_out;

    unsigned int* gid8 = (unsigned int*)d_ws;   // 8 KB

    hipMemsetAsync(out, 0, sizeof(float), stream);
    pack_gid_kernel<<<2, 1024, 0, stream>>>(group_ids, gid8);
    meta_loss_kernel<<<B_, 256, 0, stream>>>(logits, true_y, gid8, out);
}

// Round 2
// 45.284 us; speedup vs baseline: 2.2785x; 2.2785x over previous
//
#include <hip/hip_runtime.h>
#include <math.h>

// Problem constants (match reference)
constexpr int   B_    = 2048;
constexpr int   L_    = 8192;
constexpr int   G_    = 256;
constexpr float BETA_ = 0.01f;
constexpr float BIG_  = 1024.0f;   // y-flag encoding (validated absmax 0.0 in prior rounds)

constexpr int   HALF  = L_ / 2;                 // 4096 labels per half-row
constexpr int   PMAX  = HALF + G_ * 3;          // padded rank space per half = 4864 floats (19456 B)

// log(sigmoid(-x)) = -softplus(x) = -(max(x,0) + log(1 + exp(-|x|)))
__device__ __forceinline__ float log_sigmoid_neg(float x) {
    return -(fmaxf(x, 0.0f) + __logf(1.0f + __expf(-fabsf(x))));
}

// ---------------------------------------------------------------------------
// Prep: counting sort into PADDED rank space, one block per HALF-row slab.
// Each (half, group) extent padded to a multiple of 4 floats so the main
// kernel can use aligned ds_read_b128. offs[h][g+1]-offs[h][g] = ceil(n/4)*4.
// Total per half <= 4096 + 3*256 = 4864 (u16-safe).
// ---------------------------------------------------------------------------
extern "C" __global__ __launch_bounds__(1024)
void build_rank_kernel(const int* __restrict__ group_ids,
                       int* __restrict__ g_offs,          // [2][257]
                       unsigned short* __restrict__ g_rank) // [8192], rank within half
{
    __shared__ int s_cnt[G_];
    __shared__ int s_scan[G_];
    __shared__ int s_cur[G_];

    const int t = threadIdx.x;          // 0..1023
    const int h = blockIdx.x;           // 0..1

    if (t < G_) s_cnt[t] = 0;

    const int4 ids = ((const int4*)group_ids)[h * 1024 + t];   // 4 labels/thread
    __syncthreads();

    atomicAdd(&s_cnt[ids.x], 1);
    atomicAdd(&s_cnt[ids.y], 1);
    atomicAdd(&s_cnt[ids.z], 1);
    atomicAdd(&s_cnt[ids.w], 1);
    __syncthreads();

    // inclusive scan over PADDED counts
    if (t < G_) s_scan[t] = (s_cnt[t] + 3) & ~3;
    __syncthreads();
    for (int off = 1; off < G_; off <<= 1) {
        int v = 0;
        if (t < G_ && t >= off) v = s_scan[t - off];
        __syncthreads();
        if (t < G_) s_scan[t] += v;
        __syncthreads();
    }

    if (t < G_) {
        const int excl = s_scan[t] - ((s_cnt[t] + 3) & ~3);   // padded start
        s_cur[t] = excl;
        g_offs[h * 257 + t] = excl;
    }
    if (t == 0) g_offs[h * 257 + G_] = s_scan[G_ - 1];
    __syncthreads();

    // rank within half (order within group irrelevant for a sum)
    const int l = h * HALF + t * 4;
    g_rank[l + 0] = (unsigned short)atomicAdd(&s_cur[ids.x], 1);
    g_rank[l + 1] = (unsigned short)atomicAdd(&s_cur[ids.y], 1);
    g_rank[l + 2] = (unsigned short)atomicAdd(&s_cur[ids.z], 1);
    g_rank[l + 3] = (unsigned short)atomicAdd(&s_cur[ids.w], 1);
}

// NOTE: ranks written with stride-4 per thread (not ushort4-coalesced) — the
// main kernel reads them as ushort4; label l's rank must sit at g_rank[l].
// Writes above are t*4.. t*4+3 — contiguous per thread, coalesced per wave
// in 8B chunks via two b32 stores; acceptable for a 16 KB one-time write.

// ---------------------------------------------------------------------------
// Main: one 256-thread block (4 waves) per HALF-row.
//  - LDS 19.5 KB -> 8 blocks/CU -> 32 waves/CU (100% occupancy).
//  - Phase 1: coalesced float4/int4 loads, encode, scatter b32 into padded
//    rank space. Phase 2: ALL 256 threads, aligned ds_read_b128 contiguous
//    per-group extents (avg 4 iters). One global atomicAdd per (b,g) half —
//    exactly 2 adders per address -> deterministic f32 sum.
// ---------------------------------------------------------------------------
extern "C" __global__ __launch_bounds__(256, 8)
void meta_loss_kernel(const float* __restrict__ logits,
                      const int*   __restrict__ true_y,
                      const int*   __restrict__ g_offs,
                      const unsigned short* __restrict__ g_rank,
                      float*       __restrict__ partial)   // [B][G]
{
    __shared__ float s_row[PMAX];            // 19456 B

    const int t = threadIdx.x;               // 0..255
    const int b = blockIdx.x >> 1;
    const int h = blockIdx.x & 1;

    const float4*  lg = (const float4*)(logits + (size_t)b * L_ + h * HALF);
    const int4*    ty = (const int4*)(true_y + (size_t)b * L_ + h * HALF);
    const ushort4* rk = (const ushort4*)(g_rank + h * HALF);
    float4* s_row4 = (float4*)s_row;

    // group extent for this half (L2-hot)
    const int o0 = g_offs[h * 257 + t];
    const int o1 = g_offs[h * 257 + t + 1];

    // zero-init padded rank space: 1216 float4 over 256 threads
    #pragma unroll
    for (int i = 0; i < 5; ++i) {
        const int j = i * 256 + t;
        if (j < PMAX / 4) s_row4[j] = make_float4(0.f, 0.f, 0.f, 0.f);
    }
    __syncthreads();

    // ---- Phase 1: stream slab -> padded-permuted encoded LDS ----
    #pragma unroll
    for (int i = 0; i < HALF / (4 * 256); ++i) {          // 4 iters
        const int idx = i * 256 + t;
        const float4  x = lg[idx];
        const int4    y = ty[idx];
        const ushort4 r = rk[idx];
        s_row[r.x] = log_sigmoid_neg(x.x) + (y.x ? BIG_ : 0.0f);
        s_row[r.y] = log_sigmoid_neg(x.y) + (y.y ? BIG_ : 0.0f);
        s_row[r.z] = log_sigmoid_neg(x.z) + (y.z ? BIG_ : 0.0f);
        s_row[r.w] = log_sigmoid_neg(x.w) + (y.w ? BIG_ : 0.0f);
    }
    __syncthreads();

    // ---- Phase 2: vectorized contiguous per-group sum (all 256 threads) ----
    float4 a4 = make_float4(0.f, 0.f, 0.f, 0.f);
    for (int j = o0; j < o1; j += 4) {
        const float4 v = *(const float4*)&s_row[j];
        a4.x += v.x; a4.y += v.y; a4.z += v.z; a4.w += v.w;
    }
    const float enc = (a4.x + a4.y) + (a4.z + a4.w);

    if (o1 > o0)                              // skip groups empty in this half
        atomicAdd(&partial[b * G_ + t], enc);
}

// ---------------------------------------------------------------------------
// Finalize: decode BIG encoding, BCE terms, global reduce. 2 MB read, tiny.
// ---------------------------------------------------------------------------
extern "C" __global__ __launch_bounds__(1024)
void finalize_kernel(const float* __restrict__ partial,
                     float* __restrict__ out)
{
    __shared__ float s_part[16];

    const int t   = threadIdx.x;
    const int idx = blockIdx.x * 1024 + t;    // 512 blocks x 1024 = 524288

    const float enc = partial[idx];
    const int   k   = __float2int_rn(enc * (1.0f / BIG_));   // # true labels
    const float gl  = enc - BIG_ * (float)k;                 // sum log(1-sig)

    float term;
    if (k != 0) {
        term = fmaxf(gl, -100.0f);                    // meta_y = 1: log(p)
    } else {
        // empty/all-false group: gl<=0; gl==0 -> log1p(-1) = -inf -> clamp
        term = fmaxf(log1pf(-__expf(gl)), -100.0f);   // meta_y = 0
    }

    #pragma unroll
    for (int off = 32; off > 0; off >>= 1)
        term += __shfl_down(term, off, 64);
    if ((t & 63) == 0) s_part[t >> 6] = term;
    __syncthreads();

    if (t == 0) {
        float s = 0.0f;
        #pragma unroll
        for (int w = 0; w < 16; ++w) s += s_part[w];
        atomicAdd(out, s * (-BETA_ / ((float)B_ * (float)G_)));
    }
}

extern "C" void kernel_launch(void* const* d_in, const int* in_sizes, int n_in,
                              void* d_out, int out_size, void* d_ws, size_t ws_size,
                              hipStream_t stream) {
    const float* logits    = (const float*)d_in[0];
    const int*   true_y    = (const int*)d_in[1];
    const int*   group_ids = (const int*)d_in[2];
    float*       out       = (float*)d_out;

    // workspace layout:
    //   [0, 2MB)            partial [2048][256] f32
    //   [2MB, 2MB+16KB)     g_rank u16
    //   [2MB+16KB, +2.1KB)  g_offs [2][257] int
    float*          partial = (float*)d_ws;
    unsigned short* g_rank  = (unsigned short*)((char*)d_ws + (size_t)B_ * G_ * 4);
    int*            g_offs  = (int*)((char*)d_ws + (size_t)B_ * G_ * 4 + L_ * 2);

    hipMemsetAsync(partial, 0, (size_t)B_ * G_ * 4, stream);
    hipMemsetAsync(out, 0, sizeof(float), stream);

    build_rank_kernel<<<2, 1024, 0, stream>>>(group_ids, g_offs, g_rank);
    meta_loss_kernel<<<2 * B_, 256, 0, stream>>>(logits, true_y, g_offs, g_rank, partial);
    finalize_kernel<<<(B_ * G_) / 1024, 1024, 0, stream>>>(partial, out);
}